// Round 7
// baseline (728.749 us; speedup 1.0000x reference)
//
#include <hip/hip_runtime.h>
#include <hip/hip_bf16.h>
#include <stdint.h>

#define N_ATOMS 65536
#define N_BONDS 131072
#define N_MOLS  512
#define D_IN    16
#define DD      128
#define REPEAT  3

typedef __attribute__((ext_vector_type(8))) short s8b;
typedef __attribute__((ext_vector_type(4))) float f32x4;

__device__ __forceinline__ float us2f(unsigned short s) {
    unsigned int u = ((unsigned int)s) << 16;
    float f; __builtin_memcpy(&f, &u, 4); return f;
}
__device__ __forceinline__ unsigned short f2us(float f) {
    __hip_bfloat16 h = __float2bfloat16(f);
    unsigned short s; __builtin_memcpy(&s, &h, 2); return s;
}
__device__ __forceinline__ void acc8(float* a, uint4 v) {
    unsigned short w[8]; __builtin_memcpy(w, &v, 16);
#pragma unroll
    for (int j = 0; j < 8; j++) a[j] += us2f(w[j]);
}

// ---------------- one-time prep ----------------

// Pack W[K][128] fp32 -> bf16 fragment order: Wpk[(((c*4+ks)*4+quad)*128 + n)*8 + j]
// where k = c*128 + ks*32 + quad*8 + j. B-frag (c,ks,quad,col) = 16 B contiguous.
__global__ void k_pack_w(const float* __restrict__ W, unsigned short* __restrict__ Wpk, int K) {
    int idx = blockIdx.x * 256 + threadIdx.x;     // K*128
    if (idx >= K * 128) return;
    int k = idx >> 7, n = idx & 127;
    int c = k >> 7, ks = (k >> 5) & 3, quad = (k >> 3) & 3, j = k & 7;
    int pidx = (((c * 4 + ks) * 4 + quad) * 128 + n) * 8 + j;
    Wpk[pidx] = f2us(W[k * 128 + n]);
}

__global__ void k_deg(const int* __restrict__ bsrc, const int* __restrict__ bdst,
                      int* __restrict__ deg) {
    int e = blockIdx.x * 256 + threadIdx.x;
    atomicAdd(&deg[bsrc[e]], 1);
    atomicAdd(&deg[bdst[e]], 1);
}

__global__ void k_scan(const int* __restrict__ deg, int* __restrict__ rowptr,
                       int* __restrict__ cursor) {
    __shared__ int part[1024];
    int t = threadIdx.x;
    int base = t * 64;
    int s = 0;
    for (int i = 0; i < 64; i++) s += deg[base + i];
    part[t] = s;
    __syncthreads();
    if (t == 0) {
        int run = 0;
        for (int i = 0; i < 1024; i++) { int v = part[i]; part[i] = run; run += v; }
    }
    __syncthreads();
    int off = part[t];
    for (int i = 0; i < 64; i++) {
        rowptr[base + i] = off;
        cursor[base + i] = off;
        off += deg[base + i];
    }
    if (t == 1023) rowptr[N_ATOMS] = off;
}

__global__ void k_fill(const int* __restrict__ bsrc, const int* __restrict__ bdst,
                       int* __restrict__ cursor, int* __restrict__ adj) {
    int e = blockIdx.x * 256 + threadIdx.x;
    int p = atomicAdd(&cursor[bsrc[e]], 1); adj[p] = e;
    int q = atomicAdd(&cursor[bdst[e]], 1); adj[q] = e;
}

// mol_ptr[m] = lower_bound(ids, m); one block >= 513 threads
__global__ void k_molptr(const int* __restrict__ ids, int rows, int* __restrict__ mptr) {
    int m = threadIdx.x;
    if (m > N_MOLS) return;
    int lo = 0, hi = rows;
    while (lo < hi) {
        int mid = (lo + hi) >> 1;
        if (ids[mid] < m) lo = mid + 1; else hi = mid;
    }
    mptr[m] = lo;
}

// ---------------- init ----------------

__global__ void k_init_edges(const float* __restrict__ bo, const float* __restrict__ Wfe,
                             const float* __restrict__ bfe,
                             unsigned short* __restrict__ he, unsigned short* __restrict__ he0) {
    int idx = blockIdx.x * 256 + threadIdx.x;
    int e = idx >> 7, d = idx & 127;
    unsigned short v = f2us(fmaxf(fmaf(bo[e], Wfe[d], bfe[d]), 0.f));
    he[idx] = v; he0[idx] = v;
}

__global__ void k_init_nodes(const float* __restrict__ atoms, const float* __restrict__ Wfv,
                             const float* __restrict__ bfv,
                             unsigned short* __restrict__ hv, unsigned short* __restrict__ hv0) {
    int idx = blockIdx.x * 256 + threadIdx.x;
    int n = idx >> 7, d = idx & 127;
    float acc = bfv[d];
#pragma unroll
    for (int k = 0; k < D_IN; k++)
        acc = fmaf(atoms[n*D_IN + k], Wfv[k*DD + d], acc);
    unsigned short v = f2us(fmaxf(acc, 0.f));
    hv[idx] = v; hv0[idx] = v;
}

// split per-molecule sum: S contiguous sub-ranges per mol; one atomic per col per block.
__global__ __launch_bounds__(256) void k_molsum_s(const unsigned short* __restrict__ x,
                                                  const int* __restrict__ mptr,
                                                  float* __restrict__ out, int S) {
    __shared__ float red[16 * 128];
    int m = blockIdx.x / S, s = blockIdx.x - m * S;
    int b = mptr[m], e = mptr[m + 1];
    int len = (e - b + S - 1) / S;
    int r0 = b + s * len;
    int r1 = min(r0 + len, e);
    int rl = threadIdx.x >> 4, g = threadIdx.x & 15;
    float acc[8] = {0,0,0,0,0,0,0,0};
    for (int r = r0 + rl; r < r1; r += 16)
        acc8(acc, *reinterpret_cast<const uint4*>(x + (size_t)r * DD + g * 8));
#pragma unroll
    for (int j = 0; j < 8; j++) red[rl * 128 + g * 8 + j] = acc[j];
    __syncthreads();
    if (threadIdx.x < 128) {
        int col = threadIdx.x;
        float sum = 0.f;
#pragma unroll
        for (int i = 0; i < 16; i++) sum += red[i * 128 + col];
        atomicAdd(&out[(size_t)m * DD + col], sum);
    }
}

__global__ void k_mol_init(const float* __restrict__ ns, const float* __restrict__ Wfu,
                           const float* __restrict__ bfu, float* __restrict__ hu0) {
    int idx = blockIdx.x * 256 + threadIdx.x;
    int m = idx >> 7, d = idx & 127;
    float acc = bfu[d];
    for (int k = 0; k < DD; k++)
        acc = fmaf(ns[m*DD + k], Wfu[k*DD + d], acc);
    hu0[idx] = fmaxf(acc, 0.f);
}

// per-round tiny GEMM: y[m][d] = bias[d] + sum_k hu[m][k]*W[(row0+k)*128+d]
__global__ void k_yrow(const float* __restrict__ hu, const float* __restrict__ W,
                       const float* __restrict__ bias, float* __restrict__ y, int row0) {
    int idx = blockIdx.x * 256 + threadIdx.x;   // M*D
    int m = idx >> 7, d = idx & 127;
    float acc = bias[d];
    for (int k = 0; k < DD; k++)
        acc = fmaf(hu[m*DD + k], W[(row0 + k)*DD + d], acc);
    y[idx] = acc;
}

// ---------------- phi_e (MFMA, zero-LDS, direct global A-frags) ----------------
// he[e] <- relu([h_e | h_e0 | h_v[src] | h_v[dst]] @ We[0:512] + yue[bmol[e]]), in place.
// Block = 128 rows x 128 cols, 4 waves; wave wv owns cols wv*32..+31 (nt=2), all rows (mt=8).
// A-frag = direct 16 B global load (row l15 of tile, koff ks*32+quad*8). B from packed WeP.
__global__ __launch_bounds__(256) void k_phi_e(
        unsigned short* __restrict__ he, const unsigned short* __restrict__ he0,
        const unsigned short* __restrict__ hv,
        const unsigned short* __restrict__ Wpk, const float* __restrict__ yue,
        const int* __restrict__ bsrc, const int* __restrict__ bdst,
        const int* __restrict__ bmol) {
    int tid = threadIdx.x;
    int e0 = blockIdx.x * 128;
    int wv = tid >> 6, lane = tid & 63, quad = lane >> 4, l15 = lane & 15;

    // per-lane gather row indices (lane needs row mt*16+l15 of the tile)
    int srow[8], drow[8];
#pragma unroll
    for (int mt = 0; mt < 8; mt++) {
        srow[mt] = bsrc[e0 + mt*16 + l15];
        drow[mt] = bdst[e0 + mt*16 + l15];
    }

    f32x4 acc[8][2];
#pragma unroll
    for (int mt = 0; mt < 8; mt++) {
        acc[mt][0] = (f32x4){0.f, 0.f, 0.f, 0.f};
        acc[mt][1] = (f32x4){0.f, 0.f, 0.f, 0.f};
    }

    const unsigned short* heB  = he  + (size_t)e0 * DD;
    const unsigned short* he0B = he0 + (size_t)e0 * DD;

#pragma unroll
    for (int c = 0; c < 4; c++) {
#pragma unroll
        for (int ks = 0; ks < 4; ks++) {
            int koff = ks * 32 + quad * 8;
            const unsigned short* wb = Wpk + ((c * 4 + ks) * 4 + quad) * 1024 + (wv * 32 + l15) * 8;
            s8b b0 = *reinterpret_cast<const s8b*>(wb);
            s8b b1 = *reinterpret_cast<const s8b*>(wb + 128);   // +16 cols
            s8b afr[8];
#pragma unroll
            for (int mt = 0; mt < 8; mt++) {
                const unsigned short* ap;
                if      (c == 0) ap = heB  + (size_t)(mt*16 + l15) * DD + koff;
                else if (c == 1) ap = he0B + (size_t)(mt*16 + l15) * DD + koff;
                else if (c == 2) ap = hv   + (size_t)srow[mt] * DD + koff;
                else             ap = hv   + (size_t)drow[mt] * DD + koff;
                afr[mt] = *reinterpret_cast<const s8b*>(ap);
            }
#pragma unroll
            for (int mt = 0; mt < 8; mt++) {
                acc[mt][0] = __builtin_amdgcn_mfma_f32_16x16x32_bf16(afr[mt], b0, acc[mt][0], 0, 0, 0);
                acc[mt][1] = __builtin_amdgcn_mfma_f32_16x16x32_bf16(afr[mt], b1, acc[mt][1], 0, 0, 0);
            }
        }
    }

    __syncthreads();   // all chunk-0 reads of he complete before in-place writes

    // epilogue: C/D layout col=lane&15, row=quad*4+reg
#pragma unroll
    for (int mt = 0; mt < 8; mt++) {
#pragma unroll
        for (int r = 0; r < 4; r++) {
            int row = e0 + mt*16 + quad*4 + r;
            const float* yrow = yue + (size_t)bmol[row] * DD;
#pragma unroll
            for (int nt = 0; nt < 2; nt++) {
                int col = wv*32 + nt*16 + l15;
                float v = acc[mt][nt][r] + yrow[col];
                he[(size_t)row * DD + col] = f2us(fmaxf(v, 0.f));
            }
        }
    }
}

// ---------------- e_bar_i gather (CSR, vectorized, unroll-4) ----------------
__global__ __launch_bounds__(256) void k_ebar(const unsigned short* __restrict__ he,
                                              const int* __restrict__ rowptr,
                                              const int* __restrict__ adj,
                                              unsigned short* __restrict__ ebar_i) {
    int n = blockIdx.x * 16 + (threadIdx.x >> 4);
    int g = threadIdx.x & 15;
    int b = rowptr[n], e = rowptr[n + 1];
    float acc[8] = {0,0,0,0,0,0,0,0};
    int j = b;
    for (; j + 3 < e; j += 4) {
        uint4 v0 = *reinterpret_cast<const uint4*>(he + (size_t)adj[j]     * DD + g * 8);
        uint4 v1 = *reinterpret_cast<const uint4*>(he + (size_t)adj[j + 1] * DD + g * 8);
        uint4 v2 = *reinterpret_cast<const uint4*>(he + (size_t)adj[j + 2] * DD + g * 8);
        uint4 v3 = *reinterpret_cast<const uint4*>(he + (size_t)adj[j + 3] * DD + g * 8);
        acc8(acc, v0); acc8(acc, v1); acc8(acc, v2); acc8(acc, v3);
    }
    for (; j < e; j++)
        acc8(acc, *reinterpret_cast<const uint4*>(he + (size_t)adj[j] * DD + g * 8));
    unsigned short o[8];
#pragma unroll
    for (int k = 0; k < 8; k++) o[k] = f2us(acc[k]);
    uint4 ov; __builtin_memcpy(&ov, o, 16);
    *reinterpret_cast<uint4*>(ebar_i + (size_t)n * DD + g * 8) = ov;
}

// ---------------- phi_v (MFMA, zero-LDS, 3 contiguous chunks) ----------------
// hv[n] <- relu([h_v | h_v0 | ebar_i] @ Wv[0:384] + yuv[amol[n]]), in place.
__global__ __launch_bounds__(256) void k_phi_v(
        unsigned short* __restrict__ hv, const unsigned short* __restrict__ hv0,
        const unsigned short* __restrict__ ebar_i,
        const unsigned short* __restrict__ Wpk, const float* __restrict__ yuv,
        const int* __restrict__ amol) {
    int tid = threadIdx.x;
    int n0 = blockIdx.x * 128;
    int wv = tid >> 6, lane = tid & 63, quad = lane >> 4, l15 = lane & 15;

    f32x4 acc[8][2];
#pragma unroll
    for (int mt = 0; mt < 8; mt++) {
        acc[mt][0] = (f32x4){0.f, 0.f, 0.f, 0.f};
        acc[mt][1] = (f32x4){0.f, 0.f, 0.f, 0.f};
    }

    const unsigned short* bases[3] = {
        hv + (size_t)n0 * DD, hv0 + (size_t)n0 * DD, ebar_i + (size_t)n0 * DD
    };

#pragma unroll
    for (int c = 0; c < 3; c++) {
        const unsigned short* xb = bases[c];
#pragma unroll
        for (int ks = 0; ks < 4; ks++) {
            int koff = ks * 32 + quad * 8;
            const unsigned short* wb = Wpk + ((c * 4 + ks) * 4 + quad) * 1024 + (wv * 32 + l15) * 8;
            s8b b0 = *reinterpret_cast<const s8b*>(wb);
            s8b b1 = *reinterpret_cast<const s8b*>(wb + 128);
            s8b afr[8];
#pragma unroll
            for (int mt = 0; mt < 8; mt++)
                afr[mt] = *reinterpret_cast<const s8b*>(xb + (size_t)(mt*16 + l15) * DD + koff);
#pragma unroll
            for (int mt = 0; mt < 8; mt++) {
                acc[mt][0] = __builtin_amdgcn_mfma_f32_16x16x32_bf16(afr[mt], b0, acc[mt][0], 0, 0, 0);
                acc[mt][1] = __builtin_amdgcn_mfma_f32_16x16x32_bf16(afr[mt], b1, acc[mt][1], 0, 0, 0);
            }
        }
    }

    __syncthreads();   // chunk-0 reads of hv complete before in-place writes

#pragma unroll
    for (int mt = 0; mt < 8; mt++) {
#pragma unroll
        for (int r = 0; r < 4; r++) {
            int row = n0 + mt*16 + quad*4 + r;
            const float* yrow = yuv + (size_t)amol[row] * DD;
#pragma unroll
            for (int nt = 0; nt < 2; nt++) {
                int col = wv*32 + nt*16 + l15;
                float v = acc[mt][nt][r] + yrow[col];
                hv[(size_t)row * DD + col] = f2us(fmaxf(v, 0.f));
            }
        }
    }
}

// ---------------- phi_u ----------------
__global__ void k_phi_u(const float* __restrict__ hu_in, const float* __restrict__ hu0,
                        const float* __restrict__ ebar, const float* __restrict__ vbar,
                        const float* __restrict__ Wu, const float* __restrict__ bu,
                        float* __restrict__ hu_out, float* __restrict__ dout) {
    int idx = blockIdx.x * 256 + threadIdx.x;
    int m = idx >> 7, d = idx & 127;
    float acc = bu[d];
    const float* segs[4] = { hu_in + m*DD, hu0 + m*DD, ebar + m*DD, vbar + m*DD };
    for (int s = 0; s < 4; s++) {
        const float* x = segs[s];
        const float* W = Wu + (s*DD)*DD + d;
        for (int k = 0; k < DD; k++)
            acc = fmaf(x[k], W[k*DD], acc);
    }
    float v = fmaxf(acc, 0.f);
    hu_out[idx] = v;
    dout[idx] = v;
}

// ---------------- launch ----------------

extern "C" void kernel_launch(void* const* d_in, const int* in_sizes, int n_in,
                              void* d_out, int out_size, void* d_ws, size_t ws_size,
                              hipStream_t stream) {
    const float* atoms = (const float*)d_in[0];
    const float* bo    = (const float*)d_in[1];
    const float* Wfe   = (const float*)d_in[2];
    const float* bfe   = (const float*)d_in[3];
    const float* Wfv   = (const float*)d_in[4];
    const float* bfv   = (const float*)d_in[5];
    const float* Wfu   = (const float*)d_in[6];
    const float* bfu   = (const float*)d_in[7];
    const float* We    = (const float*)d_in[8];
    const float* be    = (const float*)d_in[9];
    const float* Wv    = (const float*)d_in[10];
    const float* bv    = (const float*)d_in[11];
    const float* Wu    = (const float*)d_in[12];
    const float* bu    = (const float*)d_in[13];
    const int* bsrc    = (const int*)d_in[14];
    const int* bdst    = (const int*)d_in[15];
    const int* amol    = (const int*)d_in[16];
    const int* bmol    = (const int*)d_in[17];

    char* p = (char*)d_ws;
    auto alloc = [&](size_t bytes) {
        char* r = p;
        p += (bytes + 255) & ~(size_t)255;
        return r;
    };
    unsigned short* he     = (unsigned short*)alloc((size_t)N_BONDS * DD * 2);
    unsigned short* he0b   = (unsigned short*)alloc((size_t)N_BONDS * DD * 2);
    unsigned short* hv     = (unsigned short*)alloc((size_t)N_ATOMS * DD * 2);
    unsigned short* hv0b   = (unsigned short*)alloc((size_t)N_ATOMS * DD * 2);
    unsigned short* ebar_i = (unsigned short*)alloc((size_t)N_ATOMS * DD * 2);
    unsigned short* WeP    = (unsigned short*)alloc((size_t)640 * DD * 2);
    unsigned short* WvP    = (unsigned short*)alloc((size_t)512 * DD * 2);
    int* deg      = (int*)alloc((size_t)N_ATOMS * 4);
    int* rowptr   = (int*)alloc((size_t)(N_ATOMS + 1) * 4);
    int* cursor   = (int*)alloc((size_t)N_ATOMS * 4);
    int* adj      = (int*)alloc((size_t)2 * N_BONDS * 4);
    int* bmol_ptr = (int*)alloc((size_t)(N_MOLS + 1) * 4);
    int* amol_ptr = (int*)alloc((size_t)(N_MOLS + 1) * 4);
    float* node_sum = (float*)alloc((size_t)N_MOLS * DD * 4);
    float* hu0   = (float*)alloc((size_t)N_MOLS * DD * 4);
    float* huA   = (float*)alloc((size_t)N_MOLS * DD * 4);
    float* huB   = (float*)alloc((size_t)N_MOLS * DD * 4);
    float* ebar  = (float*)alloc((size_t)N_MOLS * DD * 4);
    float* vbar  = (float*)alloc((size_t)N_MOLS * DD * 4);
    float* yue   = (float*)alloc((size_t)N_MOLS * DD * 4);
    float* yuv   = (float*)alloc((size_t)N_MOLS * DD * 4);

    // ---- CSR + mol ranges ----
    hipMemsetAsync(deg, 0, (size_t)N_ATOMS * 4, stream);
    k_deg<<<N_BONDS/256, 256, 0, stream>>>(bsrc, bdst, deg);
    k_scan<<<1, 1024, 0, stream>>>(deg, rowptr, cursor);
    k_fill<<<N_BONDS/256, 256, 0, stream>>>(bsrc, bdst, cursor, adj);
    k_molptr<<<1, 1024, 0, stream>>>(bmol, N_BONDS, bmol_ptr);
    k_molptr<<<1, 1024, 0, stream>>>(amol, N_ATOMS, amol_ptr);

    // ---- weight packing ----
    k_pack_w<<<(640*DD)/256, 256, 0, stream>>>(We, WeP, 640);
    k_pack_w<<<(512*DD)/256, 256, 0, stream>>>(Wv, WvP, 512);

    // ---- init ----
    k_init_edges<<<(N_BONDS*DD)/256, 256, 0, stream>>>(bo, Wfe, bfe, he, he0b);
    k_init_nodes<<<(N_ATOMS*DD)/256, 256, 0, stream>>>(atoms, Wfv, bfv, hv, hv0b);
    hipMemsetAsync(node_sum, 0, (size_t)N_MOLS * DD * 4, stream);
    k_molsum_s<<<N_MOLS*2, 256, 0, stream>>>(hv, amol_ptr, node_sum, 2);
    k_mol_init<<<(N_MOLS*DD)/256, 256, 0, stream>>>(node_sum, Wfu, bfu, hu0);

    const float* hu_in = hu0; float* hu_out = huA;

    for (int r = 0; r < REPEAT; r++) {
        k_yrow<<<(N_MOLS*DD)/256, 256, 0, stream>>>(hu_in, We, be, yue, 512);
        k_yrow<<<(N_MOLS*DD)/256, 256, 0, stream>>>(hu_in, Wv, bv, yuv, 384);
        hipMemsetAsync(ebar, 0, (size_t)N_MOLS * DD * 4, stream);
        hipMemsetAsync(vbar, 0, (size_t)N_MOLS * DD * 4, stream);

        k_phi_e<<<N_BONDS/128, 256, 0, stream>>>(he, he0b, hv, WeP, yue,
                                                 bsrc, bdst, bmol);
        k_ebar<<<N_ATOMS/16, 256, 0, stream>>>(he, rowptr, adj, ebar_i);
        k_molsum_s<<<N_MOLS*4, 256, 0, stream>>>(he, bmol_ptr, ebar, 4);
        k_phi_v<<<N_ATOMS/128, 256, 0, stream>>>(hv, hv0b, ebar_i, WvP, yuv, amol);
        k_molsum_s<<<N_MOLS*2, 256, 0, stream>>>(hv, amol_ptr, vbar, 2);
        k_phi_u<<<(N_MOLS*DD)/256, 256, 0, stream>>>(hu_in, hu0, ebar, vbar, Wu, bu,
                                                     hu_out, (float*)d_out);

        hu_in = hu_out; hu_out = (hu_out == huA) ? huB : huA;
    }
}